// Round 2
// 259.409 us; speedup vs baseline: 1.0757x; 1.0757x over previous
//
#include <hip/hip_runtime.h>

#define B_    4096
#define P_    64
#define OBS_  128
#define HID_  256
#define ACTD_ 32

typedef __attribute__((ext_vector_type(8)))  __bf16 bf16x8;
typedef __attribute__((ext_vector_type(2)))  __bf16 bf16x2_t;
typedef __attribute__((ext_vector_type(4)))  float  f32x4;
typedef __attribute__((ext_vector_type(16))) float  f32x16;

#define XSTRIDE 264   // bf16 elems; 16B-aligned rows, bank-group-balanced

// ws layout (bf16 elems)
#define WS1 0L
#define WS2 2097152L
#define WS3 6291456L
#define WS4 10485760L

#if defined(__has_builtin)
#if __has_builtin(__builtin_amdgcn_cvt_pk_bf16_f32)
#define HAVE_CVT_PK_BF16 1
#endif
#endif
#ifndef HAVE_CVT_PK_BF16
#define HAVE_CVT_PK_BF16 0
#endif

// Integer RNE fp32->bf16. PROVEN on HW (rounds 2/6-11, absmax 0.0390625).
__device__ __forceinline__ unsigned short f2bf(float x) {
    unsigned u = __builtin_bit_cast(unsigned, x);
    u = (u + 0x7fffu + ((u >> 16) & 1u)) >> 16;   // RNE
    return (unsigned short)u;
}

// Pack two fp32 -> bf16x2 (RNE): lo16 = bf16(a), hi16 = bf16(b).
__device__ __forceinline__ unsigned pack_bf16_rne(float a, float b) {
#if HAVE_CVT_PK_BF16
    bf16x2_t p = __builtin_amdgcn_cvt_pk_bf16_f32(a, b);
    return __builtin_bit_cast(unsigned, p);
#else
    unsigned ua = __builtin_bit_cast(unsigned, a);
    unsigned ub = __builtin_bit_cast(unsigned, b);
    ua = ua + 0x7fffu + ((ua >> 16) & 1u);
    ub = ub + 0x7fffu + ((ub >> 16) & 1u);
    return __builtin_amdgcn_perm(ub, ua, 0x07060302u);
#endif
}

// Paired ELU via raw inline asm — PROVEN (rounds 8-11). Back-to-back exps +
// s_nop 0 cover the trans-op hazard. Compiler-generated ELUs miscompute
// (r3/4/5); keep asm verbatim.
__device__ __forceinline__ void elu2_asm(float &a, float &b) {
    float ra, rb;
    asm volatile(
        "v_mul_f32 %0, 0x3fb8aa3b, %2\n\t"
        "v_mul_f32 %1, 0x3fb8aa3b, %3\n\t"
        "v_exp_f32 %0, %0\n\t"
        "v_exp_f32 %1, %1\n\t"
        "s_nop 0\n\t"
        "v_add_f32 %0, -1.0, %0\n\t"
        "v_add_f32 %1, -1.0, %1\n\t"
        "v_cmp_lt_f32 vcc, 0, %2\n\t"
        "v_cndmask_b32 %0, %0, %2, vcc\n\t"
        "v_cmp_lt_f32 vcc, 0, %3\n\t"
        "v_cndmask_b32 %1, %1, %3, vcc"
        : "=&v"(ra), "=&v"(rb) : "v"(a), "v"(b) : "vcc");
    a = ra; b = rb;
}

// -------- fused weight prep: fp32 [P][K][N] -> bf16 [P][K/32][4 u][N][8 j] --------
// NATURAL k order everywhere (transposed epilogue writes X in natural column
// order, so no k-permutation is needed for any layer).
template<int K, int N>
__device__ __forceinline__ void prep_body(const float* __restrict__ W,
                                          unsigned short* __restrict__ out,
                                          int b, int t)
{
    constexpr int CH = K / 32;
    int tid  = b * 256 + t;
    int n    = tid % N;
    int rest = tid / N;
    int u    = rest % 4;
    rest    /= 4;
    int c    = rest % CH;
    int p    = rest / CH;
    const float* __restrict__ src = W + ((long)(p * K + c * 32 + u * 8)) * N + n;
    unsigned short tmp[8];
#pragma unroll
    for (int j = 0; j < 8; ++j)
        tmp[j] = f2bf(src[(long)j * N]);
    unsigned short* dst = out + ((((long)(p * CH + c) * 4 + u) * N + n) * 8);
    *reinterpret_cast<uint4*>(dst) = *reinterpret_cast<const uint4*>(tmp);
}

extern "C" __global__ __launch_bounds__(256)
void prep_all(const float* __restrict__ W1, const float* __restrict__ W2,
              const float* __restrict__ W3, const float* __restrict__ W4,
              unsigned short* __restrict__ ws)
{
    int b = blockIdx.x, t = threadIdx.x;
    if      (b < 1024) prep_body<128, 256>(W1, ws + WS1, b,        t);
    else if (b < 3072) prep_body<256, 256>(W2, ws + WS2, b - 1024, t);
    else if (b < 5120) prep_body<256, 256>(W3, ws + WS3, b - 3072, t);
    else               prep_body<256, 32 >(W4, ws + WS4, b - 5120, t);
}

// -------- one 256-wide fused layer, TRANSPOSED output (C^T = W^T X^T) --------
// mfma(W_frag, X_frag): channel lands on the reg-mapped D row, batch on the
// lane dim. GroupNorm's 256-channel reduction is thread-local (32 chans) +
// 8-way LDS partial combine — NO LDS transpose pass, NO cross-half shuffle.
// acc[nt][mt][4q+e]: channel = w*64 + 4h + nt*32 + 8q + e ; batch = mt*32+l5.
template<int KCH>
__device__ __forceinline__ void layer256(
    unsigned short* __restrict__ X,
    const char* __restrict__ wsrc,
    const float* __restrict__ bp, const float* __restrict__ gp, const float* __restrict__ bep,
    float2* __restrict__ part, float2* __restrict__ stats,
    int tid, bool elu)
{
    const int w  = tid >> 6;         // wave 0..3 -> channel stripe 64w..64w+63
    const int l5 = tid & 31;         // batch row within m-tile
    const int h  = (tid & 63) >> 5;  // lane half -> k-offset 8h / chan-offset 4h

    const bf16x8* __restrict__ Wp = (const bf16x8*)wsrc + (h * 256 + w * 64 + l5);
    const int nb = w * 64 + 4 * h;

    // ---- bias folded into accumulator init (mathematically = post-add) ----
    f32x16 acc[2][2];
#pragma unroll
    for (int nt = 0; nt < 2; ++nt)
#pragma unroll
        for (int q = 0; q < 4; ++q) {
            const float4 b4 = *reinterpret_cast<const float4*>(bp + nb + nt * 32 + 8 * q);
#pragma unroll
            for (int mt = 0; mt < 2; ++mt) {
                acc[nt][mt][4 * q + 0] = b4.x;
                acc[nt][mt][4 * q + 1] = b4.y;
                acc[nt][mt][4 * q + 2] = b4.z;
                acc[nt][mt][4 * q + 3] = b4.w;
            }
        }

#pragma unroll
    for (int c = 0; c < KCH; ++c) {
        const int k0 = c * 16 + h * 8;
        bf16x8 x0 = *(const bf16x8*)(X + l5 * XSTRIDE + k0);
        bf16x8 x1 = *(const bf16x8*)(X + (32 + l5) * XSTRIDE + k0);
        bf16x8 w0 = Wp[c * 512];
        bf16x8 w1 = Wp[c * 512 + 32];
        acc[0][0] = __builtin_amdgcn_mfma_f32_32x32x16_bf16(w0, x0, acc[0][0], 0, 0, 0);
        acc[0][1] = __builtin_amdgcn_mfma_f32_32x32x16_bf16(w0, x1, acc[0][1], 0, 0, 0);
        acc[1][0] = __builtin_amdgcn_mfma_f32_32x32x16_bf16(w1, x0, acc[1][0], 0, 0, 0);
        acc[1][1] = __builtin_amdgcn_mfma_f32_32x32x16_bf16(w1, x1, acc[1][1], 0, 0, 0);
    }
    __syncthreads();   // all waves' X reads complete before the epilogue rewrites X

    // ---- scalar per-row partial sums over this thread's 32 channels ----
    float s0 = 0.f, s20 = 0.f, s1 = 0.f, s21 = 0.f;
#pragma unroll
    for (int nt = 0; nt < 2; ++nt)
#pragma unroll
        for (int r = 0; r < 16; ++r) {
            float v0 = acc[nt][0][r];
            float v1 = acc[nt][1][r];
            s0 += v0;  s20 = fmaf(v0, v0, s20);
            s1 += v1;  s21 = fmaf(v1, v1, s21);
        }
    // publish BOTH rows' partials directly (no cross-half shuffle): 8 per row.
    part[l5 * 9 + w * 2 + h]        = make_float2(s0, s20);   // row l5
    part[(32 + l5) * 9 + w * 2 + h] = make_float2(s1, s21);   // row 32+l5
    __syncthreads();
    if (w == 0) {
        const int lane = tid & 63;
        float s = 0.f, s2 = 0.f;
#pragma unroll
        for (int i = 0; i < 8; ++i) {
            float2 pp = part[lane * 9 + i];
            s += pp.x; s2 += pp.y;
        }
        float mu  = s * (1.f / 256.f);
        float var = s2 * (1.f / 256.f) - mu * mu;
        stats[lane] = make_float2(mu, rsqrtf(var + 1e-5f));
    }
    __syncthreads();

    // ---- normalize + ELU + in-place X update (natural column order) ----
    const float2 st0 = stats[l5], st1 = stats[32 + l5];   // 2 reads (was 32)
#pragma unroll
    for (int nt = 0; nt < 2; ++nt) {
#pragma unroll
        for (int q = 0; q < 4; ++q) {
            const int nq = nb + nt * 32 + 8 * q;
            const float4 g4 = *reinterpret_cast<const float4*>(gp  + nq);
            const float4 e4 = *reinterpret_cast<const float4*>(bep + nq);
#pragma unroll
            for (int mt = 0; mt < 2; ++mt) {
                const float mu = mt ? st1.x : st0.x;
                const float rs = mt ? st1.y : st0.y;
                float v0 = (acc[nt][mt][4 * q + 0] - mu) * rs * g4.x + e4.x;
                float v1 = (acc[nt][mt][4 * q + 1] - mu) * rs * g4.y + e4.y;
                float v2 = (acc[nt][mt][4 * q + 2] - mu) * rs * g4.z + e4.z;
                float v3 = (acc[nt][mt][4 * q + 3] - mu) * rs * g4.w + e4.w;
                if (elu) { elu2_asm(v0, v1); elu2_asm(v2, v3); }
                uint2 pk;
                pk.x = pack_bf16_rne(v0, v1);
                pk.y = pack_bf16_rne(v2, v3);
                *reinterpret_cast<uint2*>(X + (mt * 32 + l5) * XSTRIDE + nq) = pk;
            }
        }
    }
    __syncthreads();   // stripe writes visible before next layer's X reads
}

// -------- final layer: N=32, 16x16x32 MFMA, direct-global B, no barriers --------
__device__ __forceinline__ void layer32(
    const unsigned short* __restrict__ X,
    const char* __restrict__ wsrc,
    const float* __restrict__ bp, const float* __restrict__ gp, const float* __restrict__ bep,
    float* __restrict__ outg, int bbase, int p, int tid)
{
    const int w = tid >> 6, lane = tid & 63, ln = lane & 15, quad = lane >> 4;
    const bf16x8* __restrict__ Bp = (const bf16x8*)wsrc + (quad * 32 + ln);

    // bias folded into accumulator init (C/D col = lane&15 = n)
    const float bb0 = bp[ln], bb1 = bp[16 + ln];
    f32x4 acc[2];
#pragma unroll
    for (int r = 0; r < 4; ++r) { acc[0][r] = bb0; acc[1][r] = bb1; }

#pragma unroll
    for (int c = 0; c < 8; ++c) {
        bf16x8 a  = *(const bf16x8*)(X + (16 * w + ln) * XSTRIDE + c * 32 + quad * 8);
        bf16x8 b0 = Bp[c * 128];
        bf16x8 b1 = Bp[c * 128 + 16];
        acc[0] = __builtin_amdgcn_mfma_f32_16x16x32_bf16(a, b0, acc[0], 0, 0, 0);
        acc[1] = __builtin_amdgcn_mfma_f32_16x16x32_bf16(a, b1, acc[1], 0, 0, 0);
    }

    const float g0 = gp[ln], g1 = gp[16 + ln], be0 = bep[ln], be1 = bep[16 + ln];
#pragma unroll
    for (int r = 0; r < 4; ++r) {
        float y0 = acc[0][r], y1 = acc[1][r];
        float s = y0 + y1, s2 = y0 * y0 + y1 * y1;
        s += __shfl_xor(s, 1);  s2 += __shfl_xor(s2, 1);
        s += __shfl_xor(s, 2);  s2 += __shfl_xor(s2, 2);
        s += __shfl_xor(s, 4);  s2 += __shfl_xor(s2, 4);
        s += __shfl_xor(s, 8);  s2 += __shfl_xor(s2, 8);
        float mu  = s * (1.f / 32.f);
        float var = s2 * (1.f / 32.f) - mu * mu;
        float rs  = rsqrtf(var + 1e-5f);
        const int row = bbase + 16 * w + quad * 4 + r;
        float* o = outg + ((long)row * P_ + p) * ACTD_;
        o[ln]      = (y0 - mu) * rs * g0 + be0;
        o[16 + ln] = (y1 - mu) * rs * g1 + be1;
    }
}

extern "C" __global__ void __launch_bounds__(256, 4)
policy_fused(const float* __restrict__ obs,
             const unsigned short* __restrict__ wbf,
             const float* __restrict__ b1, const float* __restrict__ g1, const float* __restrict__ be1,
             const float* __restrict__ b2, const float* __restrict__ g2, const float* __restrict__ be2,
             const float* __restrict__ b3, const float* __restrict__ g3, const float* __restrict__ be3,
             const float* __restrict__ b4, const float* __restrict__ g4, const float* __restrict__ be4,
             float* __restrict__ out)
{
    __shared__ __align__(16) unsigned short X[64 * XSTRIDE];   // 33.8 KB
    __shared__ float2 part[64 * 9];                            // 4.6 KB, 9-stride pad
    __shared__ float2 stats[64];
    // total ~38.4 KB -> 4 blocks/CU

    const int tid = threadIdx.x;
    const int bx  = blockIdx.x;
    const int p     = ((bx & 7) << 3) | ((bx >> 3) & 7);   // XCD-locality swizzle
    const int bbase = (bx >> 6) * 64;

    const char* ws1 = (const char*)(wbf + WS1 + (long)p * (128 * 256));
    const char* ws2 = (const char*)(wbf + WS2 + (long)p * (256 * 256));
    const char* ws3 = (const char*)(wbf + WS3 + (long)p * (256 * 256));
    const char* ws4 = (const char*)(wbf + WS4 + (long)p * (256 * 32));

    // obs staging: natural column order (all weights natural-k now)
    for (int idx = tid; idx < 64 * 32; idx += 256) {
        int row = idx >> 5, c4 = idx & 31;
        float4 v = *reinterpret_cast<const float4*>(obs + (long)(bbase + row) * OBS_ + c4 * 4);
        uint2 pk;
        pk.x = pack_bf16_rne(v.x, v.y);
        pk.y = pack_bf16_rne(v.z, v.w);
        *reinterpret_cast<uint2*>(X + row * XSTRIDE + c4 * 4) = pk;
    }
    __syncthreads();

    layer256<8>(X, ws1, b1 + p * 256, g1 + p * 256, be1 + p * 256, part, stats, tid, true);
    layer256<16>(X, ws2, b2 + p * 256, g2 + p * 256, be2 + p * 256, part, stats, tid, true);
    layer256<16>(X, ws3, b3 + p * 256, g3 + p * 256, be3 + p * 256, part, stats, tid, true);
    layer32(X, ws4, b4 + p * 32, g4 + p * 32, be4 + p * 32, out, bbase, p, tid);
}

extern "C" void kernel_launch(void* const* d_in, const int* in_sizes, int n_in,
                              void* d_out, int out_size, void* d_ws, size_t ws_size,
                              hipStream_t stream)
{
    const float* obs = (const float*)d_in[0];
    const float* W1  = (const float*)d_in[1];
    const float* b1  = (const float*)d_in[2];
    const float* g1  = (const float*)d_in[3];
    const float* be1 = (const float*)d_in[4];
    const float* W2  = (const float*)d_in[5];
    const float* b2  = (const float*)d_in[6];
    const float* g2  = (const float*)d_in[7];
    const float* be2 = (const float*)d_in[8];
    const float* W3  = (const float*)d_in[9];
    const float* b3  = (const float*)d_in[10];
    const float* g3  = (const float*)d_in[11];
    const float* be3 = (const float*)d_in[12];
    const float* W4  = (const float*)d_in[13];
    const float* b4  = (const float*)d_in[14];
    const float* g4  = (const float*)d_in[15];
    const float* be4 = (const float*)d_in[16];
    float* out = (float*)d_out;
    unsigned short* ws = (unsigned short*)d_ws;

    hipLaunchKernelGGL(prep_all, dim3(5376), dim3(256), 0, stream, W1, W2, W3, W4, ws);

    hipLaunchKernelGGL(policy_fused, dim3(4096), dim3(256), 0, stream,
                       obs, ws,
                       b1, g1, be1, b2, g2, be2, b3, g3, be3, b4, g4, be4, out);
}